// Round 2
// baseline (3857.248 us; speedup 1.0000x reference)
//
#include <hip/hip_runtime.h>
#include <hip/hip_fp16.h>

#define TT 2048
#define BB 64
#define HH 128
#define GG 512  // 4H

__device__ __forceinline__ float sigm(float x) {
    return __builtin_amdgcn_rcpf(1.0f + __expf(-x));
}
__device__ __forceinline__ float tanh_f(float x) {
    // tanh(x) = 1 - 2/(1+exp(2x)); saturates correctly at +/-inf of exp
    return 1.0f - 2.0f * __builtin_amdgcn_rcpf(1.0f + __expf(2.0f * x));
}

// Quad-gate layout: thread tid -> gate g = tid&3, hidden unit j = tid>>2,
// weight row r = g*128 + j. The 4 gates of unit j sit in adjacent lanes of one
// wave -> exchange activations with 3 quad shuffles, no LDS round-trip, and
// only ONE barrier per step (double-buffered h broadcast buffer).

// ---------------- layer 0 recurrence: 1 batch per WG ----------------
__global__ __launch_bounds__(512, 2) void k_lstm0(
    const float* __restrict__ x, const int* __restrict__ lengths,
    const float* __restrict__ ff_w, const float* __restrict__ ff_b,
    const float* __restrict__ W_ih0, const float* __restrict__ W_hh0,
    const float* __restrict__ b0, __half* __restrict__ h1) {
    const int b = blockIdx.x;
    const int tid = threadIdx.x;
    const int g = tid & 3;        // 0:i 1:f 2:g 3:o
    const int j = tid >> 2;       // hidden unit
    const int r = g * HH + j;     // gate row
    __shared__ float xs[TT];
    __shared__ float h_lds[2][HH];

    for (int i = tid; i < TT; i += GG) xs[i] = x[b * TT + i];

    // W_hh0 row r -> registers; fold rank-1 input projection: gate_x(t) = x*v + u
    float w[HH];
    float v = 0.f, u = 0.f;
    {
        const float4* wi4 = reinterpret_cast<const float4*>(W_ih0 + r * HH);
        const float4* wh4 = reinterpret_cast<const float4*>(W_hh0 + r * HH);
        const float4* fw4 = reinterpret_cast<const float4*>(ff_w);
        const float4* fb4 = reinterpret_cast<const float4*>(ff_b);
#pragma unroll
        for (int m = 0; m < HH / 4; ++m) {
            float4 a = wi4[m];
            float4 fw = fw4[m];
            float4 fb = fb4[m];
            v += a.x * fw.x + a.y * fw.y + a.z * fw.z + a.w * fw.w;
            u += a.x * fb.x + a.y * fb.y + a.z * fb.z + a.w * fb.w;
            float4 ww = wh4[m];
            w[4 * m + 0] = ww.x; w[4 * m + 1] = ww.y;
            w[4 * m + 2] = ww.z; w[4 * m + 3] = ww.w;
        }
        u += b0[r];
    }
    if (tid < HH) h_lds[0][tid] = 0.f;
    float c = 0.f;
    const int len = lengths[b];
    __syncthreads();

    for (int t = 0; t < len; ++t) {
        float a0 = 0.f, a1 = 0.f, a2 = 0.f, a3 = 0.f;  // 4 chains: hide FMA latency
        const float4* h4 = reinterpret_cast<const float4*>(h_lds[t & 1]);
#pragma unroll
        for (int m = 0; m < HH / 4; ++m) {
            float4 hv = h4[m];  // same addr across lanes -> LDS broadcast
            a0 += w[4 * m + 0] * hv.x;
            a1 += w[4 * m + 1] * hv.y;
            a2 += w[4 * m + 2] * hv.z;
            a3 += w[4 * m + 3] * hv.w;
        }
        float acc = u + xs[t] * v + ((a0 + a1) + (a2 + a3));
        float a = (g == 2) ? tanh_f(acc) : sigm(acc);
        // quad exchange: arr[d] = activation from lane (g^d)
        float t1 = __shfl_xor(a, 1);
        float t2 = __shfl_xor(a, 2);
        float t3 = __shfl_xor(t1, 2);
        float gi = (g == 0) ? a : (g == 1) ? t1 : (g == 2) ? t2 : t3;   // d = g^0
        float gf = (g == 1) ? a : (g == 0) ? t1 : (g == 3) ? t2 : t3;   // d = g^1
        float gg = (g == 2) ? a : (g == 3) ? t1 : (g == 0) ? t2 : t3;   // d = g^2
        float go = (g == 3) ? a : (g == 2) ? t1 : (g == 1) ? t2 : t3;   // d = g^3
        c = gf * c + gi * gg;                 // redundant in all 4 lanes (identical)
        float hn = go * tanh_f(c);
        if (g == 0) {
            h_lds[(t + 1) & 1][j] = hn;
            h1[(t * BB + b) * HH + j] = __float2half(hn);
        }
        __syncthreads();  // single barrier: next step reads the buffer just written
    }
}

// ---------------- layer-1 input projection GEMM: [T*B,128] @ [128,512]^T + b1 -> fp16 ----------------
// Output is scattered into quad-gate order pos(n) = ((n&127)<<2)|(n>>7) so that
// k_lstm1's per-step load g1[row*512 + tid] is fully coalesced.
__global__ __launch_bounds__(256, 2) void k_proj(
    const __half* __restrict__ h1, const float* __restrict__ W_ih1,
    const float* __restrict__ b1, __half* __restrict__ g1) {
    const int m0 = blockIdx.x * 64;
    const int n0 = blockIdx.y * 64;
    const int tid = threadIdx.x;
    const int tn = tid & 15, tm = tid >> 4;
    __shared__ float As[64 * 65];  // stride 65: conflict-free column reads
    __shared__ float Ws[64 * 65];
    float acc[4][4];
#pragma unroll
    for (int i = 0; i < 4; ++i)
#pragma unroll
        for (int jj = 0; jj < 4; ++jj) acc[i][jj] = 0.f;

    for (int ko = 0; ko < HH; ko += 64) {
#pragma unroll
        for (int p = 0; p < 8; ++p) {  // A: 64x64 halfs
            int idx2 = tid + p * 256;
            int m = idx2 >> 5, kk2 = idx2 & 31;
            __half2 hv = *reinterpret_cast<const __half2*>(h1 + (m0 + m) * HH + ko + kk2 * 2);
            float2 f = __half22float2(hv);
            As[m * 65 + 2 * kk2 + 0] = f.x;
            As[m * 65 + 2 * kk2 + 1] = f.y;
        }
#pragma unroll
        for (int p = 0; p < 4; ++p) {  // W: 64x64 floats
            int idx4 = tid + p * 256;
            int n = idx4 >> 4, kk4 = idx4 & 15;
            float4 wv = *reinterpret_cast<const float4*>(W_ih1 + (n0 + n) * HH + ko + kk4 * 4);
            Ws[n * 65 + 4 * kk4 + 0] = wv.x;
            Ws[n * 65 + 4 * kk4 + 1] = wv.y;
            Ws[n * 65 + 4 * kk4 + 2] = wv.z;
            Ws[n * 65 + 4 * kk4 + 3] = wv.w;
        }
        __syncthreads();
#pragma unroll 8
        for (int k = 0; k < 64; ++k) {
            float a0 = As[(4 * tm + 0) * 65 + k];
            float a1 = As[(4 * tm + 1) * 65 + k];
            float a2 = As[(4 * tm + 2) * 65 + k];
            float a3 = As[(4 * tm + 3) * 65 + k];
            float w0 = Ws[(4 * tn + 0) * 65 + k];
            float w1 = Ws[(4 * tn + 1) * 65 + k];
            float w2 = Ws[(4 * tn + 2) * 65 + k];
            float w3 = Ws[(4 * tn + 3) * 65 + k];
            acc[0][0] += a0 * w0; acc[0][1] += a0 * w1; acc[0][2] += a0 * w2; acc[0][3] += a0 * w3;
            acc[1][0] += a1 * w0; acc[1][1] += a1 * w1; acc[1][2] += a1 * w2; acc[1][3] += a1 * w3;
            acc[2][0] += a2 * w0; acc[2][1] += a2 * w1; acc[2][2] += a2 * w2; acc[2][3] += a2 * w3;
            acc[3][0] += a3 * w0; acc[3][1] += a3 * w1; acc[3][2] += a3 * w2; acc[3][3] += a3 * w3;
        }
        __syncthreads();
    }
    float bb[4];
#pragma unroll
    for (int q = 0; q < 4; ++q) bb[q] = b1[n0 + 4 * tn + q];
#pragma unroll
    for (int i = 0; i < 4; ++i) {
        int m = m0 + 4 * tm + i;
        __half* dst = g1 + (size_t)m * GG;
#pragma unroll
        for (int q = 0; q < 4; ++q) {
            int n = n0 + 4 * tn + q;
            int pos = ((n & 127) << 2) | (n >> 7);  // quad-gate order
            dst[pos] = __float2half(acc[i][q] + bb[q]);
        }
    }
}

// ---------------- layer 1 recurrence + fused masked mean/max/last pooling ----------------
__global__ __launch_bounds__(512, 2) void k_lstm1(
    const __half* __restrict__ g1, const int* __restrict__ lengths,
    const float* __restrict__ W_hh1, float* __restrict__ pooled) {
    const int b = blockIdx.x;
    const int tid = threadIdx.x;
    const int g = tid & 3;
    const int j = tid >> 2;
    const int r = g * HH + j;
    __shared__ float h_lds[2][HH];
    float w[HH];
    {
        const float4* wh4 = reinterpret_cast<const float4*>(W_hh1 + r * HH);
#pragma unroll
        for (int m = 0; m < HH / 4; ++m) {
            float4 ww = wh4[m];
            w[4 * m + 0] = ww.x; w[4 * m + 1] = ww.y;
            w[4 * m + 2] = ww.z; w[4 * m + 3] = ww.w;
        }
    }
    if (tid < HH) h_lds[0][tid] = 0.f;
    float c = 0.f, mean_acc = 0.f, mx = -1e30f, last = 0.f;
    const int len = lengths[b];
    __syncthreads();

    float gcur = __half2float(g1[(size_t)(0 * BB + b) * GG + tid]);  // coalesced: quad-gate order
    for (int t = 0; t < len; ++t) {
        int tnext = (t + 1 < len) ? t + 1 : t;
        __half gnx = g1[(size_t)(tnext * BB + b) * GG + tid];  // prefetch: consumed next iter
        float a0 = 0.f, a1 = 0.f, a2 = 0.f, a3 = 0.f;
        const float4* h4 = reinterpret_cast<const float4*>(h_lds[t & 1]);
#pragma unroll
        for (int m = 0; m < HH / 4; ++m) {
            float4 hv = h4[m];
            a0 += w[4 * m + 0] * hv.x;
            a1 += w[4 * m + 1] * hv.y;
            a2 += w[4 * m + 2] * hv.z;
            a3 += w[4 * m + 3] * hv.w;
        }
        float acc = gcur + ((a0 + a1) + (a2 + a3));
        float a = (g == 2) ? tanh_f(acc) : sigm(acc);
        float t1 = __shfl_xor(a, 1);
        float t2 = __shfl_xor(a, 2);
        float t3 = __shfl_xor(t1, 2);
        float gi = (g == 0) ? a : (g == 1) ? t1 : (g == 2) ? t2 : t3;
        float gf = (g == 1) ? a : (g == 0) ? t1 : (g == 3) ? t2 : t3;
        float gg = (g == 2) ? a : (g == 3) ? t1 : (g == 0) ? t2 : t3;
        float go = (g == 3) ? a : (g == 2) ? t1 : (g == 1) ? t2 : t3;
        c = gf * c + gi * gg;
        float hn = go * tanh_f(c);
        if (g == 0) h_lds[(t + 1) & 1][j] = hn;
        mean_acc += hn;                 // redundant across quad; only g==0 writes out
        mx = fmaxf(mx, hn);
        if (t == len - 1) last = hn;
        __syncthreads();
        gcur = __half2float(gnx);
    }
    if (g == 0) {
        pooled[b * 384 + j] = mean_acc / (float)len;
        pooled[b * 384 + 128 + j] = mx;
        pooled[b * 384 + 256 + j] = last;
    }
}

// ---------------- head: [B,3H] @ [3H,C]^T + bias ----------------
__global__ __launch_bounds__(448) void k_head(
    const float* __restrict__ pooled, const float* __restrict__ lin_w,
    const float* __restrict__ lin_b, float* __restrict__ out) {
    int tid = threadIdx.x;  // 448 = 64*7
    int b = tid / 7, cc = tid % 7;
    const float* p = pooled + b * 384;
    const float* wr = lin_w + cc * 384;
    float a0 = 0.f, a1 = 0.f, a2 = 0.f, a3 = 0.f;
#pragma unroll
    for (int k = 0; k < 384; k += 4) {
        a0 += p[k + 0] * wr[k + 0];
        a1 += p[k + 1] * wr[k + 1];
        a2 += p[k + 2] * wr[k + 2];
        a3 += p[k + 3] * wr[k + 3];
    }
    out[tid] = lin_b[cc] + ((a0 + a1) + (a2 + a3));
}

extern "C" void kernel_launch(void* const* d_in, const int* in_sizes, int n_in,
                              void* d_out, int out_size, void* d_ws, size_t ws_size,
                              hipStream_t stream) {
    const float* x      = (const float*)d_in[0];
    const int*   lens   = (const int*)d_in[1];
    const float* ff_w   = (const float*)d_in[2];
    const float* ff_b   = (const float*)d_in[3];
    const float* W_ih0  = (const float*)d_in[4];
    const float* W_hh0  = (const float*)d_in[5];
    const float* b0     = (const float*)d_in[6];
    const float* W_ih1  = (const float*)d_in[7];
    const float* W_hh1  = (const float*)d_in[8];
    const float* b1     = (const float*)d_in[9];
    const float* lin_w  = (const float*)d_in[10];
    const float* lin_b  = (const float*)d_in[11];
    float* out = (float*)d_out;

    // workspace carve (168 MB total)
    char* ws = (char*)d_ws;
    __half* h1 = (__half*)ws;                                   // [T*B*H] fp16 = 33.5 MB
    __half* g1 = (__half*)(ws + (size_t)TT * BB * HH * 2);      // [T*B*4H] fp16 = 134 MB
    float* pooled = (float*)(ws + (size_t)TT * BB * HH * 2 + (size_t)TT * BB * GG * 2);  // [B*384]

    k_lstm0<<<dim3(BB), dim3(GG), 0, stream>>>(x, lens, ff_w, ff_b, W_ih0, W_hh0, b0, h1);
    k_proj<<<dim3((TT * BB) / 64, GG / 64), dim3(256), 0, stream>>>(h1, W_ih1, b1, g1);
    k_lstm1<<<dim3(BB), dim3(GG), 0, stream>>>(g1, lens, W_hh1, pooled);
    k_head<<<dim3(1), dim3(448), 0, stream>>>(pooled, lin_w, lin_b, out);
}

// Round 3
// 3247.982 us; speedup vs baseline: 1.1876x; 1.1876x over previous
//
#include <hip/hip_runtime.h>
#include <hip/hip_fp16.h>

#define TT 2048
#define BB 64
#define HH 128
#define GG 512  // 4H

typedef _Float16 f16x8 __attribute__((ext_vector_type(8)));
typedef float f32x4 __attribute__((ext_vector_type(4)));

__device__ __forceinline__ float sigm(float x) {
    return __builtin_amdgcn_rcpf(1.0f + __expf(-x));
}
__device__ __forceinline__ float tanh_f(float x) {
    // tanh(x) = 1 - 2/(1+exp(2x)); saturates correctly at +/-inf of exp
    return 1.0f - 2.0f * __builtin_amdgcn_rcpf(1.0f + __expf(2.0f * x));
}

// MFMA M=1 recurrence. Per block (1 batch): G[1,512] = h[1,128] @ W_hh^T via
// mfma_f32_16x16x32_f16. N-tile t2 = GATE index (rows r = t2*128 + unit), so a
// lane's 4 accumulators are the 4 gates of unit u = 16*w + (lane&15): no
// cross-lane exchange at all. Only A-row m=0 is real; rows 1..15 are constant
// zero, so only lanes with (lane&15)==0 read A-fragments from LDS (4 masked
// ds_read_b128 per wave per step). h crosses steps as fp16 via Hb[2][128].

// ---------------- layer 0 recurrence ----------------
__global__ __launch_bounds__(512, 2) void k_lstm0(
    const float* __restrict__ x, const int* __restrict__ lengths,
    const float* __restrict__ ff_w, const float* __restrict__ ff_b,
    const float* __restrict__ W_ih0, const float* __restrict__ W_hh0,
    const float* __restrict__ b0, _Float16* __restrict__ h1) {
    const int b = blockIdx.x;
    const int tid = threadIdx.x;
    const int w = tid >> 6;       // wave 0..7
    const int lane = tid & 63;
    const int c = lane & 15;      // col within 16x16 tile
    const int lh = lane >> 4;     // k-group 0..3
    const int un = 16 * w + c;    // unit 0..127
    __shared__ float xs[TT];
    __shared__ _Float16 Hb[2][HH];

    for (int i = tid; i < TT; i += 512) xs[i] = x[b * TT + i];
    if (tid < HH) { Hb[0][tid] = (_Float16)0.f; Hb[1][tid] = (_Float16)0.f; }

    // B-frags: B[k][n]: lane holds W_perm[n = tile_col][k = kt*32 + lh*8 + j]
    // row r = t2*128 + un (t2 = gate). Also fold rank-1 input projection.
    f16x8 Bf[4][4];
    float v[4], u[4];
#pragma unroll
    for (int t2 = 0; t2 < 4; ++t2) {
        const int r = t2 * HH + un;
        const float* wr = W_hh0 + r * HH;
#pragma unroll
        for (int kt = 0; kt < 4; ++kt) {
            const float4* p4 = reinterpret_cast<const float4*>(wr + kt * 32 + lh * 8);
            float4 w0 = p4[0], w1 = p4[1];
            f16x8 bf;
            bf[0] = (_Float16)w0.x; bf[1] = (_Float16)w0.y;
            bf[2] = (_Float16)w0.z; bf[3] = (_Float16)w0.w;
            bf[4] = (_Float16)w1.x; bf[5] = (_Float16)w1.y;
            bf[6] = (_Float16)w1.z; bf[7] = (_Float16)w1.w;
            Bf[t2][kt] = bf;
        }
        const float* wi = W_ih0 + r * HH;
        float vv = 0.f, uu = 0.f;
        for (int k = 0; k < HH; ++k) { vv += wi[k] * ff_w[k]; uu += wi[k] * ff_b[k]; }
        v[t2] = vv; u[t2] = uu + b0[r];
    }
    float cst = 0.f;
    const int len = lengths[b];
    const bool ard = (c == 0);       // A-fragment reader lanes {0,16,32,48}
    const bool wr16 = (lane < 16);   // real-row (m=0) lanes; un == 16w+lane
    __syncthreads();

    for (int t = 0; t < len; ++t) {
        f16x8 av[4];
#pragma unroll
        for (int kt = 0; kt < 4; ++kt) av[kt] = (f16x8){0, 0, 0, 0, 0, 0, 0, 0};
        if (ard) {
#pragma unroll
            for (int kt = 0; kt < 4; ++kt)
                av[kt] = *reinterpret_cast<const f16x8*>(&Hb[t & 1][kt * 32 + lh * 8]);
        }
        const float xt = xs[t];
        float pre[4];
#pragma unroll
        for (int t2 = 0; t2 < 4; ++t2) {
            f32x4 acc;
            acc[0] = wr16 ? (xt * v[t2] + u[t2]) : 0.f;  // C-init only on real row m=0
            acc[1] = 0.f; acc[2] = 0.f; acc[3] = 0.f;
#pragma unroll
            for (int kt = 0; kt < 4; ++kt)
                acc = __builtin_amdgcn_mfma_f32_16x16x32_f16(av[kt], Bf[t2][kt], acc, 0, 0, 0);
            pre[t2] = acc[0];
        }
        float gi = sigm(pre[0]), gf = sigm(pre[1]);
        float gg = tanh_f(pre[2]), go = sigm(pre[3]);
        cst = gf * cst + gi * gg;
        float hn = go * tanh_f(cst);
        if (wr16) {
            Hb[(t + 1) & 1][un] = (_Float16)hn;
            h1[((size_t)t * BB + b) * HH + un] = (_Float16)hn;
        }
        __syncthreads();
    }
}

// ---------------- layer-1 input projection GEMM: [T*B,128] @ [128,512]^T + b1 -> fp16 ----------------
__global__ __launch_bounds__(256, 2) void k_proj(
    const __half* __restrict__ h1, const float* __restrict__ W_ih1,
    const float* __restrict__ b1, __half* __restrict__ g1) {
    const int m0 = blockIdx.x * 64;
    const int n0 = blockIdx.y * 64;
    const int tid = threadIdx.x;
    const int tn = tid & 15, tm = tid >> 4;
    __shared__ float As[64 * 65];  // stride 65: conflict-free column reads
    __shared__ float Ws[64 * 65];
    float acc[4][4];
#pragma unroll
    for (int i = 0; i < 4; ++i)
#pragma unroll
        for (int jj = 0; jj < 4; ++jj) acc[i][jj] = 0.f;

    for (int ko = 0; ko < HH; ko += 64) {
#pragma unroll
        for (int p = 0; p < 8; ++p) {  // A: 64x64 halfs
            int idx2 = tid + p * 256;
            int m = idx2 >> 5, kk2 = idx2 & 31;
            __half2 hv = *reinterpret_cast<const __half2*>(h1 + (m0 + m) * HH + ko + kk2 * 2);
            float2 f = __half22float2(hv);
            As[m * 65 + 2 * kk2 + 0] = f.x;
            As[m * 65 + 2 * kk2 + 1] = f.y;
        }
#pragma unroll
        for (int p = 0; p < 4; ++p) {  // W: 64x64 floats
            int idx4 = tid + p * 256;
            int n = idx4 >> 4, kk4 = idx4 & 15;
            float4 wv = *reinterpret_cast<const float4*>(W_ih1 + (n0 + n) * HH + ko + kk4 * 4);
            Ws[n * 65 + 4 * kk4 + 0] = wv.x;
            Ws[n * 65 + 4 * kk4 + 1] = wv.y;
            Ws[n * 65 + 4 * kk4 + 2] = wv.z;
            Ws[n * 65 + 4 * kk4 + 3] = wv.w;
        }
        __syncthreads();
#pragma unroll 8
        for (int k = 0; k < 64; ++k) {
            float a0 = As[(4 * tm + 0) * 65 + k];
            float a1 = As[(4 * tm + 1) * 65 + k];
            float a2 = As[(4 * tm + 2) * 65 + k];
            float a3 = As[(4 * tm + 3) * 65 + k];
            float w0 = Ws[(4 * tn + 0) * 65 + k];
            float w1 = Ws[(4 * tn + 1) * 65 + k];
            float w2 = Ws[(4 * tn + 2) * 65 + k];
            float w3 = Ws[(4 * tn + 3) * 65 + k];
            acc[0][0] += a0 * w0; acc[0][1] += a0 * w1; acc[0][2] += a0 * w2; acc[0][3] += a0 * w3;
            acc[1][0] += a1 * w0; acc[1][1] += a1 * w1; acc[1][2] += a1 * w2; acc[1][3] += a1 * w3;
            acc[2][0] += a2 * w0; acc[2][1] += a2 * w1; acc[2][2] += a2 * w2; acc[2][3] += a2 * w3;
            acc[3][0] += a3 * w0; acc[3][1] += a3 * w1; acc[3][2] += a3 * w2; acc[3][3] += a3 * w3;
        }
        __syncthreads();
    }
    float bb0 = b1[n0 + 4 * tn + 0];
    float bb1 = b1[n0 + 4 * tn + 1];
    float bb2 = b1[n0 + 4 * tn + 2];
    float bb3 = b1[n0 + 4 * tn + 3];
#pragma unroll
    for (int i = 0; i < 4; ++i) {
        int m = m0 + 4 * tm + i;
        __half2* dst = reinterpret_cast<__half2*>(g1 + (size_t)m * GG + n0 + 4 * tn);
        dst[0] = __floats2half2_rn(acc[i][0] + bb0, acc[i][1] + bb1);
        dst[1] = __floats2half2_rn(acc[i][2] + bb2, acc[i][3] + bb3);
    }
}

// ---------------- layer 1 recurrence + fused masked mean/max/last pooling ----------------
__global__ __launch_bounds__(512, 2) void k_lstm1(
    const _Float16* __restrict__ g1, const int* __restrict__ lengths,
    const float* __restrict__ W_hh1, float* __restrict__ pooled) {
    const int b = blockIdx.x;
    const int tid = threadIdx.x;
    const int w = tid >> 6;
    const int lane = tid & 63;
    const int c = lane & 15;
    const int lh = lane >> 4;
    const int un = 16 * w + c;
    __shared__ _Float16 Hb[2][HH];

    if (tid < HH) { Hb[0][tid] = (_Float16)0.f; Hb[1][tid] = (_Float16)0.f; }

    f16x8 Bf[4][4];
#pragma unroll
    for (int t2 = 0; t2 < 4; ++t2) {
        const float* wr = W_hh1 + (t2 * HH + un) * HH;
#pragma unroll
        for (int kt = 0; kt < 4; ++kt) {
            const float4* p4 = reinterpret_cast<const float4*>(wr + kt * 32 + lh * 8);
            float4 w0 = p4[0], w1 = p4[1];
            f16x8 bf;
            bf[0] = (_Float16)w0.x; bf[1] = (_Float16)w0.y;
            bf[2] = (_Float16)w0.z; bf[3] = (_Float16)w0.w;
            bf[4] = (_Float16)w1.x; bf[5] = (_Float16)w1.y;
            bf[6] = (_Float16)w1.z; bf[7] = (_Float16)w1.w;
            Bf[t2][kt] = bf;
        }
    }
    float cst = 0.f, mean_acc = 0.f, mx = -1e30f, last = 0.f;
    const int len = lengths[b];
    const bool ard = (c == 0);
    const bool wr16 = (lane < 16);
    __syncthreads();

    // prefetch projected gates for t=0 (only real-row lanes need them)
    float gc[4] = {0.f, 0.f, 0.f, 0.f};
    if (wr16) {
#pragma unroll
        for (int t2 = 0; t2 < 4; ++t2)
            gc[t2] = (float)g1[((size_t)0 * BB + b) * GG + t2 * HH + un];
    }
    for (int t = 0; t < len; ++t) {
        float gn[4] = {0.f, 0.f, 0.f, 0.f};
        const int tn = (t + 1 < len) ? t + 1 : t;
        if (wr16) {  // prefetch next step's C-init; consumed after the barrier
#pragma unroll
            for (int t2 = 0; t2 < 4; ++t2)
                gn[t2] = (float)g1[((size_t)tn * BB + b) * GG + t2 * HH + un];
        }
        f16x8 av[4];
#pragma unroll
        for (int kt = 0; kt < 4; ++kt) av[kt] = (f16x8){0, 0, 0, 0, 0, 0, 0, 0};
        if (ard) {
#pragma unroll
            for (int kt = 0; kt < 4; ++kt)
                av[kt] = *reinterpret_cast<const f16x8*>(&Hb[t & 1][kt * 32 + lh * 8]);
        }
        float pre[4];
#pragma unroll
        for (int t2 = 0; t2 < 4; ++t2) {
            f32x4 acc;
            acc[0] = gc[t2];  // 0 on non-real rows
            acc[1] = 0.f; acc[2] = 0.f; acc[3] = 0.f;
#pragma unroll
            for (int kt = 0; kt < 4; ++kt)
                acc = __builtin_amdgcn_mfma_f32_16x16x32_f16(av[kt], Bf[t2][kt], acc, 0, 0, 0);
            pre[t2] = acc[0];
        }
        float gi = sigm(pre[0]), gf = sigm(pre[1]);
        float gg = tanh_f(pre[2]), go = sigm(pre[3]);
        cst = gf * cst + gi * gg;
        float hn = go * tanh_f(cst);
        if (wr16) Hb[(t + 1) & 1][un] = (_Float16)hn;
        mean_acc += hn;
        mx = fmaxf(mx, hn);
        if (t == len - 1) last = hn;
        __syncthreads();
#pragma unroll
        for (int t2 = 0; t2 < 4; ++t2) gc[t2] = gn[t2];
    }
    if (wr16) {
        pooled[b * 384 + un] = mean_acc / (float)len;
        pooled[b * 384 + 128 + un] = mx;
        pooled[b * 384 + 256 + un] = last;
    }
}

// ---------------- head: [B,3H] @ [3H,C]^T + bias ----------------
__global__ __launch_bounds__(448) void k_head(
    const float* __restrict__ pooled, const float* __restrict__ lin_w,
    const float* __restrict__ lin_b, float* __restrict__ out) {
    int tid = threadIdx.x;  // 448 = 64*7
    int b = tid / 7, cc = tid % 7;
    const float* p = pooled + b * 384;
    const float* wr = lin_w + cc * 384;
    float a0 = 0.f, a1 = 0.f, a2 = 0.f, a3 = 0.f;
#pragma unroll
    for (int k = 0; k < 384; k += 4) {
        a0 += p[k + 0] * wr[k + 0];
        a1 += p[k + 1] * wr[k + 1];
        a2 += p[k + 2] * wr[k + 2];
        a3 += p[k + 3] * wr[k + 3];
    }
    out[tid] = lin_b[cc] + ((a0 + a1) + (a2 + a3));
}

extern "C" void kernel_launch(void* const* d_in, const int* in_sizes, int n_in,
                              void* d_out, int out_size, void* d_ws, size_t ws_size,
                              hipStream_t stream) {
    const float* x      = (const float*)d_in[0];
    const int*   lens   = (const int*)d_in[1];
    const float* ff_w   = (const float*)d_in[2];
    const float* ff_b   = (const float*)d_in[3];
    const float* W_ih0  = (const float*)d_in[4];
    const float* W_hh0  = (const float*)d_in[5];
    const float* b0     = (const float*)d_in[6];
    const float* W_ih1  = (const float*)d_in[7];
    const float* W_hh1  = (const float*)d_in[8];
    const float* b1     = (const float*)d_in[9];
    const float* lin_w  = (const float*)d_in[10];
    const float* lin_b  = (const float*)d_in[11];
    float* out = (float*)d_out;

    // workspace carve (168 MB total)
    char* ws = (char*)d_ws;
    _Float16* h1 = (_Float16*)ws;                                   // [T*B*H] fp16 = 33.5 MB
    _Float16* g1 = (_Float16*)(ws + (size_t)TT * BB * HH * 2);      // [T*B*4H] fp16 = 134 MB
    float* pooled = (float*)(ws + (size_t)TT * BB * HH * 2 + (size_t)TT * BB * GG * 2);  // [B*384]

    k_lstm0<<<dim3(BB), dim3(512), 0, stream>>>(x, lens, ff_w, ff_b, W_ih0, W_hh0, b0, h1);
    k_proj<<<dim3((TT * BB) / 64, GG / 64), dim3(256), 0, stream>>>(
        (const __half*)h1, W_ih1, b1, (__half*)g1);
    k_lstm1<<<dim3(BB), dim3(512), 0, stream>>>(g1, lens, W_hh1, pooled);
    k_head<<<dim3(1), dim3(448), 0, stream>>>(pooled, lin_w, lin_b, out);
}